// Round 3
// baseline (616.387 us; speedup 1.0000x reference)
//
#include <hip/hip_runtime.h>

// out[t, n*16+f] = relu(bias[f] + sum_{l=0}^{31} x[t-1-2l, n] * w_pn[l, f])
// w_pn = relu(w) / ||relu(w)||_2 (per filter column, over 32 lags)
//
// T=2048, N=4096, L=32, F=16, dilation=2.
//
// R3: write-stream redesign. Evidence: R0/R1/R2 (different occupancy, LDS
// width, NT vs plain stores) all pin the kernel at ~204 us = 2.9 TB/s
// combined traffic, 0.46x of the 6.3 TB/s the harness fill sustains on the
// SAME output buffer. Shared trait: 512 B store granules scattered at
// 256 KiB stride -> per-HBM-channel ~256 B at ~random channel addresses ->
// DRAM row activate per access -> ~half bandwidth. Fix: block owns a
// same-parity t-pair (t, t+2) and writes its two 256 KiB output rows
// FRONT-TO-BACK in 8 KiB chunks (sequential per stream -> row-buffer hits).
// t-pair shares 31/33 staged x rows; x re-reads ~0.5 GiB from L3 (x is
// 33.5 MB, L3-resident), overlapped with the write drain via double-buffered
// LDS staging (issue loads early, ds_write after compute).

constexpr int T = 2048;
constexpr int N = 4096;
constexpr int L = 32;
constexpr int F = 16;
constexpr int NC = 128;            // n columns per chunk
constexpr int NCHUNK = N / NC;     // 32
constexpr int NR = 33;             // staged x rows (lags for both t's of the pair)
constexpr int OUT_STRIDE = N * F;  // 65536

typedef float f4 __attribute__((ext_vector_type(4)));
typedef float f2 __attribute__((ext_vector_type(2)));

__global__ __launch_bounds__(256, 2)
void tlayer_kernel(const float* __restrict__ x,
                   const float* __restrict__ w,
                   const float* __restrict__ bias,
                   float* __restrict__ out)
{
    __shared__ __align__(16) float xs[2][NR * NC];   // 2 x 16.5 KiB
    __shared__ float sw[L * F];                      // 2 KiB
    __shared__ float sscale[F];

    const int tid = threadIdx.x;
    const int b   = blockIdx.x;
    // t-pair (t0, t0+2), same parity; covers all t in [0, 2048)
    const int t0  = (b & 1) + (b >> 1) * 4;
    const int tb  = t0 + 2;

    // ---- weight prep (redundant per block; 512 elements, trivial) ----
    sw[tid]       = fmaxf(w[tid], 0.f);
    sw[tid + 256] = fmaxf(w[tid + 256], 0.f);
    __syncthreads();
    if (tid < F) {
        float s = 0.f;
        #pragma unroll
        for (int l = 0; l < L; ++l) { float v = sw[l * F + tid]; s += v * v; }
        sscale[tid] = rsqrtf(fmaxf(s, 1e-12f));
    }
    __syncthreads();
    sw[tid]       *= sscale[tid & 15];
    sw[tid + 256] *= sscale[tid & 15];
    __syncthreads();

    const int fp = tid & 7;            // filter pair: f = 2*fp, 2*fp+1
    const int ng = tid >> 3;           // 0..31, owns n = 4*ng .. 4*ng+3 of chunk

    f2 wr[L];                          // 64 VGPRs
    #pragma unroll
    for (int l = 0; l < L; ++l)
        wr[l] = *(const f2*)(sw + l * F + fp * 2);
    const f2 b2 = *(const f2*)(bias + fp * 2);

    // ---- staging map: idx -> (r = idx>>5, c4 = idx&31); g(r) = tb-1-2r ----
    // u = 0..3 always valid (idx <= 1023 < 1056); u = 4 only for tid < 32.

    // prologue: stage chunk 0 into xs[0]
    {
        #pragma unroll
        for (int u = 0; u < 4; ++u) {
            const int idx = tid + u * 256;
            const int r = idx >> 5, c4 = idx & 31;
            const int g = tb - 1 - 2 * r;
            f4 v = {0.f, 0.f, 0.f, 0.f};
            if (g >= 0) v = *(const f4*)(x + (size_t)g * N + c4 * 4);
            *(f4*)(&xs[0][r * NC + c4 * 4]) = v;
        }
        if (tid < 32) {
            const int g = tb - 65;                     // r = 32
            f4 v = {0.f, 0.f, 0.f, 0.f};
            if (g >= 0) v = *(const f4*)(x + (size_t)g * N + tid * 4);
            *(f4*)(&xs[0][32 * NC + tid * 4]) = v;
        }
    }
    __syncthreads();

    float* orowA = out + (size_t)t0 * OUT_STRIDE;
    float* orowB = out + (size_t)tb * OUT_STRIDE;

    #pragma unroll 1
    for (int c = 0; c < NCHUNK; ++c) {
        const int cur = c & 1;

        // issue next chunk's global loads early (consumed after compute)
        f4 ld[5];
        if (c + 1 < NCHUNK) {
            const int cn1 = (c + 1) * NC;
            #pragma unroll
            for (int u = 0; u < 4; ++u) {
                const int idx = tid + u * 256;
                const int r = idx >> 5, c4 = idx & 31;
                const int g = tb - 1 - 2 * r;
                ld[u] = {0.f, 0.f, 0.f, 0.f};
                if (g >= 0) ld[u] = *(const f4*)(x + (size_t)g * N + cn1 + c4 * 4);
            }
            ld[4] = {0.f, 0.f, 0.f, 0.f};
            if (tid < 32) {
                const int g = tb - 65;
                if (g >= 0) ld[4] = *(const f4*)(x + (size_t)g * N + cn1 + tid * 4);
            }
        }

        // compute chunk c: row r serves t=tb at lag r (r<32) and t=t0 at lag r-1
        const float* xb = &xs[cur][4 * ng];
        f2 aA[4] = {b2, b2, b2, b2};       // t0
        f2 aB[4] = {b2, b2, b2, b2};       // tb
        #pragma unroll
        for (int r = 0; r < NR; ++r) {
            const f4 xv = *(const f4*)(xb + r * NC);
            if (r < L) {
                const f2 wl = wr[r];
                aB[0] += wl * xv[0]; aB[1] += wl * xv[1];
                aB[2] += wl * xv[2]; aB[3] += wl * xv[3];
            }
            if (r >= 1) {
                const f2 wl = wr[r - 1];
                aA[0] += wl * xv[0]; aA[1] += wl * xv[1];
                aA[2] += wl * xv[2]; aA[3] += wl * xv[3];
            }
        }

        // stores: n = c*NC + 4*ng + k; both rows advance sequentially with c
        const int nbase = c * NC + 4 * ng;
        #pragma unroll
        for (int k = 0; k < 4; ++k) {
            f2 rA, rB;
            rA[0] = fmaxf(aA[k][0], 0.f); rA[1] = fmaxf(aA[k][1], 0.f);
            rB[0] = fmaxf(aB[k][0], 0.f); rB[1] = fmaxf(aB[k][1], 0.f);
            *(f2*)(orowA + (size_t)(nbase + k) * F + fp * 2) = rA;
            *(f2*)(orowB + (size_t)(nbase + k) * F + fp * 2) = rB;
        }

        // write prefetched chunk into the other buffer
        if (c + 1 < NCHUNK) {
            #pragma unroll
            for (int u = 0; u < 4; ++u) {
                const int idx = tid + u * 256;
                const int r = idx >> 5, c4 = idx & 31;
                *(f4*)(&xs[cur ^ 1][r * NC + c4 * 4]) = ld[u];
            }
            if (tid < 32)
                *(f4*)(&xs[cur ^ 1][32 * NC + tid * 4]) = ld[4];
        }
        __syncthreads();
    }
}

extern "C" void kernel_launch(void* const* d_in, const int* in_sizes, int n_in,
                              void* d_out, int out_size, void* d_ws, size_t ws_size,
                              hipStream_t stream) {
    const float* x    = (const float*)d_in[0];   // [2048, 4096]
    const float* w    = (const float*)d_in[1];   // [32, 16]
    const float* bias = (const float*)d_in[2];   // [16]
    float* out = (float*)d_out;                  // [2048, 65536]

    dim3 grid(T / 2);                            // 1024 t-pair blocks
    tlayer_kernel<<<grid, 256, 0, stream>>>(x, w, bias, out);
}

// Round 5
// 561.691 us; speedup vs baseline: 1.0974x; 1.0974x over previous
//
#include <hip/hip_runtime.h>

// out[t, n*16+f] = relu(bias[f] + sum_{l=0}^{31} x[t-1-2l, n] * w_pn[l, f])
// w_pn = relu(w) / ||relu(w)||_2 (per filter column, over 32 lags)
//
// T=2048, N=4096, L=32, F=16, dilation=2.
//
// R5 = R4 resubmit (R4 bench was an infra failure: "container failed twice";
// kernel audited OOB/hang-clean, theory untested).
//
// R4: WRITE-FRONT COMPACTION. Evidence so far: R0/R1/R2 (front ~128 MiB,
// scattered) all = 204 us kernel = 2.6 TB/s; R3 (front = full 512 MiB) =
// 271 us; harness fill (compact sliding front) = 6.2 TB/s on the same
// buffer. Theory: device-wide instantaneous write-address window size
// controls DRAM row-buffer hit rate. This version: block = 16 same-parity
// t's x 64 n (8192 blocks, ngrp minor), so 128 consecutive blocks write 32
// CONTIGUOUS t-rows (8 MiB); ~512 resident blocks -> ordered sliding front
// ~32 MiB (4-16x compaction vs R1, 16x vs R3). x-reads stay tiny (98 MB,
// vs R3's 553 MB). One barrier per block; stores are contiguous 1 KiB
// f4 wave-bursts; LDS reads bank-conflict-free broadcast.

constexpr int T = 2048;
constexpr int N = 4096;
constexpr int L = 32;
constexpr int F = 16;
constexpr int BN = 64;             // n cols per block
constexpr int KT = 16;             // same-parity t's per block (t span = 32)
constexpr int NR = 47;             // staged x rows: g = t0-63+2r, r = 0..46
constexpr int RP = 68;             // LDS row pitch in floats (bank stagger)
constexpr int OUT_STRIDE = N * F;  // 65536

typedef float f4 __attribute__((ext_vector_type(4)));

__global__ __launch_bounds__(256, 2)
void tlayer_kernel(const float* __restrict__ x,
                   const float* __restrict__ w,
                   const float* __restrict__ bias,
                   float* __restrict__ out)
{
    __shared__ __align__(16) float sxs[NR * RP];   // 12.8 KB
    __shared__ float sw[L * F];                    // 2 KB
    __shared__ float sscale[F];

    const int tid  = threadIdx.x;
    const int bi   = blockIdx.x;
    const int ngrp = bi & 63;                 // minor: consecutive blocks share t-group
    const int tg   = bi >> 6;                 // 0..127
    const int t0   = (tg & 1) + (tg >> 1) * 32;   // block t's: t0 + 2i, i = 0..15
    const int n0   = ngrp * BN;

    // ---- weight prep (redundant per block; trivial) ----
    sw[tid]       = fmaxf(w[tid], 0.f);
    sw[tid + 256] = fmaxf(w[tid + 256], 0.f);
    __syncthreads();
    if (tid < F) {
        float s = 0.f;
        #pragma unroll
        for (int l = 0; l < L; ++l) { float v = sw[l * F + tid]; s += v * v; }
        sscale[tid] = rsqrtf(fmaxf(s, 1e-12f));
    }
    __syncthreads();
    sw[tid]       *= sscale[tid & 15];
    sw[tid + 256] *= sscale[tid & 15];

    // ---- stage x rows g = t0-63+2r (r = 0..46), cols n0..n0+63 ----
    // same phase as the sw scale-apply above (disjoint LDS), one barrier below
    for (int idx = tid; idx < NR * 16; idx += 256) {
        const int r  = idx >> 4;
        const int c4 = idx & 15;
        const int g  = t0 - 63 + 2 * r;       // g_max = 2017+29 = 2046 < T
        f4 v = {0.f, 0.f, 0.f, 0.f};
        if (g >= 0)
            v = *(const f4*)(x + (size_t)g * N + n0 + c4 * 4);
        *(f4*)(&sxs[r * RP + c4 * 4]) = v;
    }
    __syncthreads();

    const int fq = tid & 3;                   // filter quad: f = 4*fq .. 4*fq+3
    const int nl = tid >> 2;                  // 0..63 local n

    // weights for my 4 filters -> 128 VGPRs
    f4 wr[L];
    #pragma unroll
    for (int l = 0; l < L; ++l)
        wr[l] = *(const f4*)(sw + l * F + fq * 4);

    const f4 b4 = *(const f4*)(bias + fq * 4);
    f4 acc[KT];
    #pragma unroll
    for (int i = 0; i < KT; ++i) acc[i] = b4;

    // row r serves t_i = t0+2i at lag l = 31+i-r  (valid for i <= r <= 31+i)
    const float* xp = sxs + nl;
    #pragma unroll
    for (int r = 0; r < NR; ++r) {
        const float xv = xp[r * RP];
        #pragma unroll
        for (int i = 0; i < KT; ++i) {
            if (r >= i && r <= 31 + i) {
                acc[i] += wr[31 + i - r] * xv;
            }
        }
    }

    // ---- stores: per t, wave writes contiguous 1 KiB ----
    float* ob = out + (size_t)(n0 + nl) * F + fq * 4;
    #pragma unroll
    for (int i = 0; i < KT; ++i) {
        f4 v;
        v[0] = fmaxf(acc[i][0], 0.f);
        v[1] = fmaxf(acc[i][1], 0.f);
        v[2] = fmaxf(acc[i][2], 0.f);
        v[3] = fmaxf(acc[i][3], 0.f);
        *(f4*)(ob + (size_t)(t0 + 2 * i) * OUT_STRIDE) = v;
    }
}

extern "C" void kernel_launch(void* const* d_in, const int* in_sizes, int n_in,
                              void* d_out, int out_size, void* d_ws, size_t ws_size,
                              hipStream_t stream) {
    const float* x    = (const float*)d_in[0];   // [2048, 4096]
    const float* w    = (const float*)d_in[1];   // [32, 16]
    const float* bias = (const float*)d_in[2];   // [16]
    float* out = (float*)d_out;                  // [2048, 65536]

    dim3 grid(128 * 64);                         // 8192 blocks, ngrp minor
    tlayer_kernel<<<grid, 256, 0, stream>>>(x, w, bias, out);
}